// Round 17
// baseline (122.327 us; speedup 1.0000x reference)
//
#include <hip/hip_runtime.h>
#include <math.h>

#define TS 16
#define TO 120
#define KXT 16

typedef __attribute__((ext_vector_type(8))) short bf16x8;
typedef __attribute__((ext_vector_type(4))) float f32x4;
typedef __attribute__((ext_vector_type(4))) unsigned int u32x4;

// float -> bf16 bits, round-nearest-even (software; setup only)
__device__ __forceinline__ unsigned short f2bf(float f){
    unsigned u = __float_as_uint(f);
    unsigned r = u + 0x7FFFu + ((u >> 16) & 1u);
    return (unsigned short)(r >> 16);
}
// HW packed f32x2 -> bf16x2 (RNE), gfx950
__device__ __forceinline__ unsigned pk_bf16(float lo, float hi){
    unsigned d;
    asm("v_cvt_pk_bf16_f32 %0, %1, %2" : "=v"(d) : "v"(lo), "v"(hi));
    return d;
}
__device__ __forceinline__ bf16x8 bc(u32x4 v){
    return __builtin_bit_cast(bf16x8, v);
}
// unpack bf16 halves of a u32 to fp32 (exact)
__device__ __forceinline__ float bf_lo(unsigned v){ return __uint_as_float(v << 16); }
__device__ __forceinline__ float bf_hi(unsigned v){ return __uint_as_float(v & 0xFFFF0000u); }

// ---------------- setup: euler, zc, permuted bf16 weights + zero proj_im ---
// scratch (floats): Rm @0 (B*9), zc @256 (B*64), Wbf @1280 (32768 ushorts)
// k-permutation pi (validated r8-r16): s6 -> f = 32u+16*((s>>2)&1)+4*(s>>3)+(s&3)
// Blocks 0..16: tables. Blocks 17..: zero proj_im (region disjoint from tables).
__global__ void setup_kernel(const float* __restrict__ r, const float* __restrict__ z,
                             const float* __restrict__ W0,
                             const float* __restrict__ Wres1,
                             const float* __restrict__ Wres2,
                             float* __restrict__ scratch,
                             float4* __restrict__ pim4, int n4, int B)
{
    int blk = blockIdx.x, tid = threadIdx.x;
    if (blk >= 17){
        int i = (blk - 17)*256 + tid;
        if (i < n4) pim4[i] = make_float4(0.f, 0.f, 0.f, 0.f);
        return;
    }
    float* Rm  = scratch;
    float* zc  = scratch + 256;
    unsigned short* W1bf = (unsigned short*)(scratch + 1280);
    unsigned short* W2bf = W1bf + 4*4096;
    if (blk == 0){
        if (tid < B){
            float a = r[tid*3+0], bb = r[tid*3+1], c = r[tid*3+2];
            float ca = cosf(a), sa = sinf(a);
            float cb = cosf(bb), sb = sinf(bb);
            float cc = cosf(c), sc = sinf(c);
            float* Rb = Rm + tid*9;
            Rb[0] = ca*cb*cc - sa*sc;  Rb[1] = -ca*cb*sc - sa*cc;  Rb[2] = ca*sb;
            Rb[3] = sa*cb*cc + ca*sc;  Rb[4] = -sa*cb*sc + ca*cc;  Rb[5] = sa*sb;
            Rb[6] = -sb*cc;            Rb[7] = sb*sc;              Rb[8] = cb;
        }
        for (int e = tid; e < B*64; e += 256){
            int b = e >> 6, i = e & 63;
            float acc = 0.f;
            for (int j = 0; j < 16; j++) acc = fmaf(W0[i*19+3+j], z[b*16+j], acc);
            zc[e] = acc;
        }
    } else {
        int base = (blk - 1) * 1024;
        for (int e = base + tid; e < base + 1024; e += 256){
            int l = e >> 12, rem = e & 4095, orow = rem >> 6, s6 = rem & 63;
            int u = s6 >> 5, s = s6 & 31;
            int f = 32*u + 16*((s >> 2) & 1) + 4*(s >> 3) + (s & 3);
            int src = l*4096 + orow*64 + f;
            W1bf[e] = f2bf(Wres1[src]);
            W2bf[e] = f2bf(Wres2[src]);
        }
    }
}

// ---------------- register-resident MFMA decoder + fused splat -------------
// r16 decoder with SEMANTICALLY-NEUTRAL scheduling changes only:
//  - m-tiles processed in PAIRS with named independent accumulators and
//    alternating MFMA issue (two chains in flight -> latency of one hides
//    under issue of the other; defeats regalloc's serializing reuse).
//  - phase-2 repacks per-t directly into Hp (word-disjoint with later t's
//    C-in reads: t=0 writes words 0,1 of Hp[m][0], t=1 reads words 2,3...).
//  - W frags loaded per-pair (peak VGPR ~110 < 128 cliff).
//  - s_setprio(1) around MFMA clusters (barrier-free waves, T5 regime).
// All values computed bit-identically to r16 (validated).
__launch_bounds__(256, 1)
__global__ void decoder_kernel(const float* __restrict__ pos,
                               const float* __restrict__ W0,
                               const float* __restrict__ scratch,
                               const float* __restrict__ W1a,
                               const float* __restrict__ W1b,
                               const float* __restrict__ ampvar,
                               const float* __restrict__ amp,
                               float* __restrict__ out_proj_pos,
                               float* __restrict__ out_pos_d,
                               float* __restrict__ out_res,
                               float* __restrict__ proj_im,
                               int N)
{
    __shared__ float tile[2*TS*TS];
    const float* __restrict__ Rm = scratch;
    const float* __restrict__ zc = scratch + 256;
    const unsigned short* __restrict__ W1bf = (const unsigned short*)(scratch + 1280);
    const unsigned short* __restrict__ W2bf = W1bf + 4*4096;

    int b  = blockIdx.y;
    int wv = threadIdx.x >> 6;
    int l  = threadIdx.x & 63;
    int q  = l >> 4, c = l & 15;
    int P0 = blockIdx.x * 256 + wv * 64;

    for (int i = threadIdx.x; i < 2*TS*TS; i += 256) tile[i] = 0.f;
    __syncthreads();   // tile zeroed before any wave reaches the splat

    // ---- H0^T = zc[b] + W0[:, :3] @ pos^T, packed to bf16 ----
    u32x4 Hp[4][2];
    {
        float px[4], py[4], pz[4];
#pragma unroll
        for (int m = 0; m < 4; m++){
            int n = P0 + 16*m + c; if (n > N-1) n = N-1;
            px[m] = pos[n*3+0]; py[m] = pos[n*3+1]; pz[m] = pos[n*3+2];
        }
#pragma unroll
        for (int m = 0; m < 4; m++){
            f32x4 h[4];
#pragma unroll
            for (int t = 0; t < 4; t++)
#pragma unroll
                for (int j = 0; j < 4; j++){
                    int f = 16*t + 4*q + j;
                    float zcf = zc[b*64 + f];
                    h[t][j] = fmaf(W0[f*19+2], pz[m],
                              fmaf(W0[f*19+1], py[m],
                              fmaf(W0[f*19+0], px[m], zcf)));
                }
            Hp[m][0].x = pk_bf16(h[0][0], h[0][1]);
            Hp[m][0].y = pk_bf16(h[0][2], h[0][3]);
            Hp[m][0].z = pk_bf16(h[1][0], h[1][1]);
            Hp[m][0].w = pk_bf16(h[1][2], h[1][3]);
            Hp[m][1].x = pk_bf16(h[2][0], h[2][1]);
            Hp[m][1].y = pk_bf16(h[2][2], h[2][3]);
            Hp[m][1].z = pk_bf16(h[3][0], h[3][1]);
            Hp[m][1].w = pk_bf16(h[3][2], h[3][3]);
        }
    }

#pragma unroll 1
    for (int ly = 0; ly < 4; ly++){
        const unsigned short* __restrict__ w1l = W1bf + ly*4096;
        const unsigned short* __restrict__ w2l = W2bf + ly*4096;

#pragma unroll
        for (int p = 0; p < 2; p++){
            const int m0 = 2*p, m1 = 2*p + 1;

            // W1 frags for this pair
            bf16x8 Wf[4][2];
#pragma unroll
            for (int t = 0; t < 4; t++)
#pragma unroll
                for (int u = 0; u < 2; u++)
                    Wf[t][u] = *(const bf16x8*)(w1l + (16*t + c)*64 + 32*u + 8*q);

            bf16x8 A0 = bc(Hp[m0][0]), A1 = bc(Hp[m0][1]);
            bf16x8 C0 = bc(Hp[m1][0]), C1 = bc(Hp[m1][1]);

            // ---- phase 1 interleaved: Sa (m0) and Sc (m1) chains alternate
            f32x4 Sa[4], Sc[4];
            __builtin_amdgcn_s_setprio(1);
#pragma unroll
            for (int t = 0; t < 4; t++){
                f32x4 sa = {0.f,0.f,0.f,0.f}, sc = {0.f,0.f,0.f,0.f};
                sa = __builtin_amdgcn_mfma_f32_16x16x32_bf16(Wf[t][0], A0, sa, 0, 0, 0);
                sc = __builtin_amdgcn_mfma_f32_16x16x32_bf16(Wf[t][0], C0, sc, 0, 0, 0);
                sa = __builtin_amdgcn_mfma_f32_16x16x32_bf16(Wf[t][1], A1, sa, 0, 0, 0);
                sc = __builtin_amdgcn_mfma_f32_16x16x32_bf16(Wf[t][1], C1, sc, 0, 0, 0);
                Sa[t] = sa; Sc[t] = sc;
            }
            __builtin_amdgcn_s_setprio(0);

            // relu + pack both
            u32x4 Ta0, Ta1, Tc0, Tc1;
            Ta0.x = pk_bf16(fmaxf(Sa[0][0],0.f), fmaxf(Sa[0][1],0.f));
            Ta0.y = pk_bf16(fmaxf(Sa[0][2],0.f), fmaxf(Sa[0][3],0.f));
            Ta0.z = pk_bf16(fmaxf(Sa[1][0],0.f), fmaxf(Sa[1][1],0.f));
            Ta0.w = pk_bf16(fmaxf(Sa[1][2],0.f), fmaxf(Sa[1][3],0.f));
            Ta1.x = pk_bf16(fmaxf(Sa[2][0],0.f), fmaxf(Sa[2][1],0.f));
            Ta1.y = pk_bf16(fmaxf(Sa[2][2],0.f), fmaxf(Sa[2][3],0.f));
            Ta1.z = pk_bf16(fmaxf(Sa[3][0],0.f), fmaxf(Sa[3][1],0.f));
            Ta1.w = pk_bf16(fmaxf(Sa[3][2],0.f), fmaxf(Sa[3][3],0.f));
            Tc0.x = pk_bf16(fmaxf(Sc[0][0],0.f), fmaxf(Sc[0][1],0.f));
            Tc0.y = pk_bf16(fmaxf(Sc[0][2],0.f), fmaxf(Sc[0][3],0.f));
            Tc0.z = pk_bf16(fmaxf(Sc[1][0],0.f), fmaxf(Sc[1][1],0.f));
            Tc0.w = pk_bf16(fmaxf(Sc[1][2],0.f), fmaxf(Sc[1][3],0.f));
            Tc1.x = pk_bf16(fmaxf(Sc[2][0],0.f), fmaxf(Sc[2][1],0.f));
            Tc1.y = pk_bf16(fmaxf(Sc[2][2],0.f), fmaxf(Sc[2][3],0.f));
            Tc1.z = pk_bf16(fmaxf(Sc[3][0],0.f), fmaxf(Sc[3][1],0.f));
            Tc1.w = pk_bf16(fmaxf(Sc[3][2],0.f), fmaxf(Sc[3][3],0.f));
            bf16x8 T00 = bc(Ta0), T01 = bc(Ta1), T10 = bc(Tc0), T11 = bc(Tc1);

            // W2 frags into the same registers
#pragma unroll
            for (int t = 0; t < 4; t++)
#pragma unroll
                for (int u = 0; u < 2; u++)
                    Wf[t][u] = *(const bf16x8*)(w2l + (16*t + c)*64 + 32*u + 8*q);

            // ---- phase 2 interleaved, repack per-t straight into Hp ----
            __builtin_amdgcn_s_setprio(1);
#pragma unroll
            for (int t = 0; t < 4; t++){
                unsigned wa0 = Hp[m0][t >> 1][(t & 1)*2 + 0];
                unsigned wb0 = Hp[m0][t >> 1][(t & 1)*2 + 1];
                unsigned wa1 = Hp[m1][t >> 1][(t & 1)*2 + 0];
                unsigned wb1 = Hp[m1][t >> 1][(t & 1)*2 + 1];
                f32x4 c0, c1;
                c0[0] = bf_lo(wa0); c0[1] = bf_hi(wa0);
                c0[2] = bf_lo(wb0); c0[3] = bf_hi(wb0);
                c1[0] = bf_lo(wa1); c1[1] = bf_hi(wa1);
                c1[2] = bf_lo(wb1); c1[3] = bf_hi(wb1);
                c0 = __builtin_amdgcn_mfma_f32_16x16x32_bf16(Wf[t][0], T00, c0, 0, 0, 0);
                c1 = __builtin_amdgcn_mfma_f32_16x16x32_bf16(Wf[t][0], T10, c1, 0, 0, 0);
                c0 = __builtin_amdgcn_mfma_f32_16x16x32_bf16(Wf[t][1], T01, c0, 0, 0, 0);
                c1 = __builtin_amdgcn_mfma_f32_16x16x32_bf16(Wf[t][1], T11, c1, 0, 0, 0);
                Hp[m0][t >> 1][(t & 1)*2 + 0] = pk_bf16(c0[0], c0[1]);
                Hp[m0][t >> 1][(t & 1)*2 + 1] = pk_bf16(c0[2], c0[3]);
                Hp[m1][t >> 1][(t & 1)*2 + 0] = pk_bf16(c1[0], c1[1]);
                Hp[m1][t >> 1][(t & 1)*2 + 1] = pk_bf16(c1[2], c1[3]);
            }
            __builtin_amdgcn_s_setprio(0);
        }
    }

    // ---- epilogue: u_a[point] = sum_f W1a[a][f] * H^T[f][point] ----
    float4 fa0[4], fa1[4], fa2[4];
#pragma unroll
    for (int t = 0; t < 4; t++){
        fa0[t] = *(const float4*)(W1a +       16*t + 4*q);
        fa1[t] = *(const float4*)(W1a +  64 + 16*t + 4*q);
        fa2[t] = *(const float4*)(W1a + 128 + 16*t + 4*q);
    }
    float u0 = 0.f, u1 = 0.f, u2 = 0.f;
#pragma unroll
    for (int m = 0; m < 4; m++){
        float p0 = 0.f, p1 = 0.f, p2 = 0.f;
#pragma unroll
        for (int t = 0; t < 4; t++){
            unsigned wa = Hp[m][t >> 1][(t & 1)*2 + 0];
            unsigned wb = Hp[m][t >> 1][(t & 1)*2 + 1];
            float h0 = bf_lo(wa), h1 = bf_hi(wa), h2 = bf_lo(wb), h3 = bf_hi(wb);
            p0 = fmaf(h0, fa0[t].x, p0); p0 = fmaf(h1, fa0[t].y, p0);
            p0 = fmaf(h2, fa0[t].z, p0); p0 = fmaf(h3, fa0[t].w, p0);
            p1 = fmaf(h0, fa1[t].x, p1); p1 = fmaf(h1, fa1[t].y, p1);
            p1 = fmaf(h2, fa1[t].z, p1); p1 = fmaf(h3, fa1[t].w, p1);
            p2 = fmaf(h0, fa2[t].x, p2); p2 = fmaf(h1, fa2[t].y, p2);
            p2 = fmaf(h2, fa2[t].z, p2); p2 = fmaf(h3, fa2[t].w, p2);
        }
        p0 += __shfl_xor(p0, 16, 64); p0 += __shfl_xor(p0, 32, 64);
        p1 += __shfl_xor(p1, 16, 64); p1 += __shfl_xor(p1, 32, 64);
        p2 += __shfl_xor(p2, 16, 64); p2 += __shfl_xor(p2, 32, 64);
        if (q == m){ u0 = p0; u1 = p1; u2 = p2; }
    }

    {
        int n = P0 + 16*q + c;
        if (n < N){
            float pxs = pos[n*3+0], pys = pos[n*3+1], pzs = pos[n*3+2];
            float t0 = tanhf(u0), t1 = tanhf(u1), t2 = tanhf(u2);
            float r0 = t0*W1b[0] + t1*W1b[1] + t2*W1b[2];
            float r1 = t0*W1b[3] + t1*W1b[4] + t2*W1b[5];
            float r2 = t0*W1b[6] + t1*W1b[7] + t2*W1b[8];
            float pdx = pxs + r0, pdy = pys + r1, pdz = pzs + r2;
            const float* Rb = Rm + b*9;
            float q0 = pdx*Rb[0] + pdy*Rb[3] + pdz*Rb[6];
            float q1 = pdx*Rb[1] + pdy*Rb[4] + pdz*Rb[7];
            size_t base = (size_t)b*N + n;
            out_res[base*3+0] = r0;  out_res[base*3+1] = r1;  out_res[base*3+2] = r2;
            out_pos_d[base*3+0] = pdx; out_pos_d[base*3+1] = pdy; out_pos_d[base*3+2] = pdz;
            out_proj_pos[base*2+0] = q0; out_proj_pos[base*2+1] = q1;

            // ---- fused bilinear splat ----
            float e0 = expf(ampvar[n]);
            float e1 = expf(ampvar[N+n]);
            float inv = amp[0] / (e0 + e1);
            float v0 = e0*inv, v1 = e1*inv;
            float pyf = (q0 + 0.5f) * 255.0f;
            float pxf = (q1 + 0.5f) * 255.0f;
            float fy0 = floorf(pyf), fx0 = floorf(pxf);
            int iy = (int)fy0, ix = (int)fx0;
            float fy = pyf - fy0, fx = pxf - fx0;
            float wy[2] = {1.f - fy, fy};
            float wx[2] = {1.f - fx, fx};
#pragma unroll
            for (int dy = 0; dy < 2; dy++)
#pragma unroll
                for (int dx = 0; dx < 2; dx++){
                    float w = wy[dy]*wx[dx];
                    int yi = min(max(iy+dy, 0), 255);
                    int xi = min(max(ix+dx, 0), 255);
                    int ty = yi - TO, tx = xi - TO;
                    if ((unsigned)ty < TS && (unsigned)tx < TS){
                        atomicAdd(&tile[ty*TS + tx],         v0*w);
                        atomicAdd(&tile[TS*TS + ty*TS + tx], v1*w);
                    } else {
                        atomicAdd(&proj_im[((size_t)(b*2+0)*256 + yi)*256 + xi], v0*w);
                        atomicAdd(&proj_im[((size_t)(b*2+1)*256 + yi)*256 + xi], v1*w);
                    }
                }
        }
    }

    __syncthreads();
    for (int i = threadIdx.x; i < TS*TS; i += 256){
        int ty = i >> 4, tx = i & (TS-1);
        float v = tile[i];
        if (v != 0.f) atomicAdd(&proj_im[((size_t)(b*2+0)*256 + TO+ty)*256 + TO+tx], v);
        v = tile[TS*TS + i];
        if (v != 0.f) atomicAdd(&proj_im[((size_t)(b*2+1)*256 + TO+ty)*256 + TO+tx], v);
    }
}

// ---------------- DFT pass 1: rows, sparse-aware + LDS twiddle table -------
__launch_bounds__(256)
__global__ void dft_rows_kernel(const float* __restrict__ proj_im, float2* __restrict__ S)
{
    int b = blockIdx.y, y = blockIdx.x;
    __shared__ float2 row[256];
    __shared__ float2 tw[256];
    __shared__ unsigned long long nzm[4];
    int k = threadIdx.x;
    {
        float s, c;
        sincosf(-6.283185307179586f * (float)k / 256.0f, &s, &c);
        tw[k] = make_float2(c, s);
    }
    const float* im0 = proj_im + ((size_t)(b*2+0)*256 + y)*256;
    const float* im1 = proj_im + ((size_t)(b*2+1)*256 + y)*256;
    float2 my = make_float2(im0[k], im1[k]);
    row[k] = my;
    unsigned long long bal = __ballot(my.x != 0.f || my.y != 0.f);
    if ((k & 63) == 0) nzm[k >> 6] = bal;
    __syncthreads();

    float2 acc = make_float2(0.f, 0.f);
#pragma unroll 1
    for (int g = 0; g < 4; g++){
        unsigned long long mm = nzm[g];
        while (mm){
            int x = (g << 6) + __ffsll((long long)mm) - 1;
            mm &= mm - 1;
            float2 zv = row[x];
            float2 t = tw[(k * x) & 255];
            acc.x = fmaf(zv.x, t.x, fmaf(-zv.y, t.y, acc.x));
            acc.y = fmaf(zv.x, t.y, fmaf( zv.y, t.x, acc.y));
        }
    }
    S[((size_t)b*256 + y)*256 + k] = acc;
}

// ---------------- DFT pass 2: column-tile slab, sparse rows, IN PLACE ------
__launch_bounds__(256)
__global__ void dft_cols_kernel(float2* __restrict__ S)
{
    __shared__ float2 slab[256][KXT + 1];
    __shared__ float2 tw[256];
    __shared__ unsigned long long wmask[4];
    __shared__ int rows[256];
    __shared__ int nrows_s;
    int b = blockIdx.y, kx0 = blockIdx.x * KXT;
    int tid = threadIdx.x;
    float2* Sb = S + (size_t)b*65536;

    {
        float s, c;
        sincosf(-6.283185307179586f * (float)tid / 256.0f, &s, &c);
        tw[tid] = make_float2(c, s);
    }
#pragma unroll 1
    for (int r0 = 0; r0 < 256; r0 += 16){
        int y = r0 + (tid >> 4), j = tid & 15;
        slab[y][j] = Sb[(size_t)y*256 + kx0 + j];
    }
    __syncthreads();

    bool nz = false;
#pragma unroll
    for (int j = 0; j < KXT; j++){
        float2 v = slab[tid][j];
        nz = nz || (v.x != 0.f) || (v.y != 0.f);
    }
    unsigned long long m = __ballot(nz);
    int wv = tid >> 6, lane = tid & 63;
    if (lane == 0) wmask[wv] = m;
    __syncthreads();
    if (nz){
        int off = 0;
        for (int w2 = 0; w2 < 4; w2++) if (w2 < wv) off += __popcll(wmask[w2]);
        unsigned long long below = (lane == 0) ? 0ULL : (m & ((1ULL << lane) - 1ULL));
        off += __popcll(below);
        rows[off] = tid;
    }
    if (tid == 0){
        int n = 0;
        for (int w2 = 0; w2 < 4; w2++) n += __popcll(wmask[w2]);
        nrows_s = n;
    }
    __syncthreads();
    int nr = nrows_s;

    int ky = tid;
    float2 acc[KXT];
#pragma unroll
    for (int j = 0; j < KXT; j++) acc[j] = make_float2(0.f, 0.f);
#pragma unroll 1
    for (int r = 0; r < nr; r++){
        int y = rows[r];
        float2 t = tw[(ky * y) & 255];
#pragma unroll
        for (int j = 0; j < KXT; j++){
            float2 zv = slab[y][j];
            acc[j].x = fmaf(zv.x, t.x, fmaf(-zv.y, t.y, acc[j].x));
            acc[j].y = fmaf(zv.x, t.y, fmaf( zv.y, t.x, acc[j].y));
        }
    }
#pragma unroll
    for (int j = 0; j < KXT; j++)
        Sb[(size_t)ky*256 + kx0 + j] = acc[j];   // Z[b][ky][kx]
}

// ---------------- Hermitian unpack + CTF filter + channel sum --------------
__launch_bounds__(256)
__global__ void combine_kernel(const float2* __restrict__ Z,
                               const float* __restrict__ A, const float* __restrict__ Bc,
                               float* __restrict__ outP, int pairs)
{
    int gid = blockIdx.x*256 + threadIdx.x;
    int b = gid >> 16;
    int lin = gid & 65535;
    int ky = lin >> 8, kx = lin & 255;
    int mky = (256 - ky) & 255, mkx = (256 - kx) & 255;
    int mlin = mky*256 + mkx;
    if (lin > mlin) return;   // pair owner only
    const float2* Zb = Z + (size_t)b*65536;
    float2 Zk = Zb[lin];
    float2 Zm = Zb[mlin];
    float Er = 0.5f*(Zk.x + Zm.x), Ei = 0.5f*(Zk.y - Zm.y);
    float Or = 0.5f*(Zk.y + Zm.y), Oi = 0.5f*(Zm.x - Zk.x);
    float fy = (ky < 128) ? (float)ky : (float)(ky - 256);
    float fx = (kx < 128) ? (float)kx : (float)(kx - 256);
    float rad = rintf(sqrtf(fy*fy + fx*fx));
    float a0 = A[0], a1 = A[1], b0 = Bc[0], b1 = Bc[1];
    float F0 = a0*a0*expf(-b0*b0*rad);
    float F1 = a1*a1*expf(-b1*b1*rad);
    float2 P = make_float2(fmaf(F0, Er, F1*Or), fmaf(F0, Ei, F1*Oi));
    if (pairs){
        float2* O = (float2*)outP + (size_t)b*65536;
        O[lin] = P;
        if (mlin != lin) O[mlin] = make_float2(P.x, -P.y);
    } else {
        float* O = outP + (size_t)b*65536;
        O[lin] = P.x;
        if (mlin != lin) O[mlin] = P.x;
    }
}

extern "C" void kernel_launch(void* const* d_in, const int* in_sizes, int n_in,
                              void* d_out, int out_size, void* d_ws, size_t ws_size,
                              hipStream_t stream)
{
    const float* z      = (const float*)d_in[0];
    const float* r      = (const float*)d_in[1];
    const float* pos    = (const float*)d_in[2];
    const float* amp    = (const float*)d_in[3];
    const float* ampvar = (const float*)d_in[4];
    const float* W0     = (const float*)d_in[5];
    const float* Wres1  = (const float*)d_in[6];
    const float* Wres2  = (const float*)d_in[7];
    const float* W1a    = (const float*)d_in[8];
    const float* W1b    = (const float*)d_in[9];
    const float* A      = (const float*)d_in[10];
    const float* Bc     = (const float*)d_in[11];

    int B = in_sizes[0] / 16;     // 16
    int N = in_sizes[2] / 3;      // 20000

    size_t nIm = (size_t)B * 65536;
    long long tailSz   = (long long)(2*nIm) + 8LL*B*N;
    long long projSize = (long long)out_size - tailSz;
    int pairs = (projSize >= (long long)(2*nIm)) ? 1 : 0;

    float* out = (float*)d_out;
    float* out_proj    = out;
    float* out_projim  = out + projSize;
    float* out_projpos = out_projim + 2*nIm;          // B*N*2
    float* out_posd    = out_projpos + (size_t)B*N*2; // B*N*3
    float* out_res     = out_posd    + (size_t)B*N*3; // B*N*3

    float* scratch = out_proj;   // dead until dft_rows; decoder consumes first

    float2* S;
    if (pairs)                                         S = (float2*)out_proj;
    else if (ws_size >= (size_t)(2*nIm)*sizeof(float)) S = (float2*)d_ws;
    else                                               S = (float2*)out_proj;

    int n4 = (int)(2*nIm/4);
    int zblocks = (n4 + 255)/256;
    setup_kernel<<<17 + zblocks, 256, 0, stream>>>(r, z, W0, Wres1, Wres2,
                                                   scratch, (float4*)out_projim,
                                                   n4, B);

    dim3 dgrid((N + 255)/256, B);
    decoder_kernel<<<dgrid, 256, 0, stream>>>(pos, W0, scratch, W1a, W1b,
                                              ampvar, amp,
                                              out_projpos, out_posd, out_res,
                                              out_projim, N);

    dim3 fgrid(256, B);
    dft_rows_kernel<<<fgrid, 256, 0, stream>>>(out_projim, S);
    dim3 cgrid(256/KXT, B);
    dft_cols_kernel<<<cgrid, 256, 0, stream>>>(S);
    combine_kernel<<<(int)(nIm/256), 256, 0, stream>>>(S, A, Bc, out_proj, pairs);
}

// Round 18
// 95.004 us; speedup vs baseline: 1.2876x; 1.2876x over previous
//
#include <hip/hip_runtime.h>
#include <math.h>

#define TS 16
#define TO 120
#define KXT 16

typedef __attribute__((ext_vector_type(8))) short bf16x8;
typedef __attribute__((ext_vector_type(4))) float f32x4;
typedef __attribute__((ext_vector_type(4))) unsigned int u32x4;

// float -> bf16 bits, round-nearest-even (software; setup only)
__device__ __forceinline__ unsigned short f2bf(float f){
    unsigned u = __float_as_uint(f);
    unsigned r = u + 0x7FFFu + ((u >> 16) & 1u);
    return (unsigned short)(r >> 16);
}
// HW packed f32x2 -> bf16x2 (RNE), gfx950
__device__ __forceinline__ unsigned pk_bf16(float lo, float hi){
    unsigned d;
    asm("v_cvt_pk_bf16_f32 %0, %1, %2" : "=v"(d) : "v"(lo), "v"(hi));
    return d;
}
__device__ __forceinline__ bf16x8 bc(u32x4 v){
    return __builtin_bit_cast(bf16x8, v);
}
// unpack bf16 halves of a u32 to fp32 (exact)
__device__ __forceinline__ float bf_lo(unsigned v){ return __uint_as_float(v << 16); }
__device__ __forceinline__ float bf_hi(unsigned v){ return __uint_as_float(v & 0xFFFF0000u); }

// ---------------- setup: euler, zc, permuted bf16 weights + zero proj_im ---
// scratch (floats): Rm @0 (B*9), zc @256 (B*64), Wbf @1280 (32768 ushorts)
// k-permutation pi (validated r8-r16): s6 -> f = 32u+16*((s>>2)&1)+4*(s>>3)+(s&3)
// Blocks 0..16: tables. Blocks 17..: zero proj_im (validated r17).
__global__ void setup_kernel(const float* __restrict__ r, const float* __restrict__ z,
                             const float* __restrict__ W0,
                             const float* __restrict__ Wres1,
                             const float* __restrict__ Wres2,
                             float* __restrict__ scratch,
                             float4* __restrict__ pim4, int n4, int B)
{
    int blk = blockIdx.x, tid = threadIdx.x;
    if (blk >= 17){
        int i = (blk - 17)*256 + tid;
        if (i < n4) pim4[i] = make_float4(0.f, 0.f, 0.f, 0.f);
        return;
    }
    float* Rm  = scratch;
    float* zc  = scratch + 256;
    unsigned short* W1bf = (unsigned short*)(scratch + 1280);
    unsigned short* W2bf = W1bf + 4*4096;
    if (blk == 0){
        if (tid < B){
            float a = r[tid*3+0], bb = r[tid*3+1], c = r[tid*3+2];
            float ca = cosf(a), sa = sinf(a);
            float cb = cosf(bb), sb = sinf(bb);
            float cc = cosf(c), sc = sinf(c);
            float* Rb = Rm + tid*9;
            Rb[0] = ca*cb*cc - sa*sc;  Rb[1] = -ca*cb*sc - sa*cc;  Rb[2] = ca*sb;
            Rb[3] = sa*cb*cc + ca*sc;  Rb[4] = -sa*cb*sc + ca*cc;  Rb[5] = sa*sb;
            Rb[6] = -sb*cc;            Rb[7] = sb*sc;              Rb[8] = cb;
        }
        for (int e = tid; e < B*64; e += 256){
            int b = e >> 6, i = e & 63;
            float acc = 0.f;
            for (int j = 0; j < 16; j++) acc = fmaf(W0[i*19+3+j], z[b*16+j], acc);
            zc[e] = acc;
        }
    } else {
        int base = (blk - 1) * 1024;
        for (int e = base + tid; e < base + 1024; e += 256){
            int l = e >> 12, rem = e & 4095, orow = rem >> 6, s6 = rem & 63;
            int u = s6 >> 5, s = s6 & 31;
            int f = 32*u + 16*((s >> 2) & 1) + 4*(s >> 3) + (s & 3);
            int src = l*4096 + orow*64 + f;
            W1bf[e] = f2bf(Wres1[src]);
            W2bf[e] = f2bf(Wres2[src]);
        }
    }
}

// ---------------- register-resident MFMA decoder + fused splat -------------
// EXACT r16 decoder (best measured: 73us). 4 waves/block, 64 points/wave.
// Hidden state packed bf16 in u32x4 Hp[4][2]; per layer all 16 weight frags
// loaded up-front (W2f latency hides under phase-1), phase1/2 fused per m.
// r17's pair-interleave + setprio REGRESSED (73->110us) and is reverted.
__launch_bounds__(256, 1)
__global__ void decoder_kernel(const float* __restrict__ pos,
                               const float* __restrict__ W0,
                               const float* __restrict__ scratch,
                               const float* __restrict__ W1a,
                               const float* __restrict__ W1b,
                               const float* __restrict__ ampvar,
                               const float* __restrict__ amp,
                               float* __restrict__ out_proj_pos,
                               float* __restrict__ out_pos_d,
                               float* __restrict__ out_res,
                               float* __restrict__ proj_im,
                               int N)
{
    __shared__ float tile[2*TS*TS];
    const float* __restrict__ Rm = scratch;
    const float* __restrict__ zc = scratch + 256;
    const unsigned short* __restrict__ W1bf = (const unsigned short*)(scratch + 1280);
    const unsigned short* __restrict__ W2bf = W1bf + 4*4096;

    int b  = blockIdx.y;
    int wv = threadIdx.x >> 6;
    int l  = threadIdx.x & 63;
    int q  = l >> 4, c = l & 15;
    int P0 = blockIdx.x * 256 + wv * 64;

    for (int i = threadIdx.x; i < 2*TS*TS; i += 256) tile[i] = 0.f;
    __syncthreads();   // tile zeroed before any wave reaches the splat

    // ---- H0^T = zc[b] + W0[:, :3] @ pos^T, packed to bf16 ----
    u32x4 Hp[4][2];
    {
        float px[4], py[4], pz[4];
#pragma unroll
        for (int m = 0; m < 4; m++){
            int n = P0 + 16*m + c; if (n > N-1) n = N-1;
            px[m] = pos[n*3+0]; py[m] = pos[n*3+1]; pz[m] = pos[n*3+2];
        }
#pragma unroll
        for (int m = 0; m < 4; m++){
            f32x4 h[4];
#pragma unroll
            for (int t = 0; t < 4; t++)
#pragma unroll
                for (int j = 0; j < 4; j++){
                    int f = 16*t + 4*q + j;
                    float zcf = zc[b*64 + f];
                    h[t][j] = fmaf(W0[f*19+2], pz[m],
                              fmaf(W0[f*19+1], py[m],
                              fmaf(W0[f*19+0], px[m], zcf)));
                }
            Hp[m][0].x = pk_bf16(h[0][0], h[0][1]);
            Hp[m][0].y = pk_bf16(h[0][2], h[0][3]);
            Hp[m][0].z = pk_bf16(h[1][0], h[1][1]);
            Hp[m][0].w = pk_bf16(h[1][2], h[1][3]);
            Hp[m][1].x = pk_bf16(h[2][0], h[2][1]);
            Hp[m][1].y = pk_bf16(h[2][2], h[2][3]);
            Hp[m][1].z = pk_bf16(h[3][0], h[3][1]);
            Hp[m][1].w = pk_bf16(h[3][2], h[3][3]);
        }
    }

#pragma unroll 1
    for (int ly = 0; ly < 4; ly++){
        const unsigned short* __restrict__ w1l = W1bf + ly*4096;
        const unsigned short* __restrict__ w2l = W2bf + ly*4096;

        // ---- all 16 weight frags issued up-front; W2f latency hides under
        //      the phase-1 MFMAs of the m-loop below ----
        bf16x8 W1f[4][2], W2f[4][2];
#pragma unroll
        for (int t = 0; t < 4; t++)
#pragma unroll
            for (int u = 0; u < 2; u++){
                W1f[t][u] = *(const bf16x8*)(w1l + (16*t + c)*64 + 32*u + 8*q);
                W2f[t][u] = *(const bf16x8*)(w2l + (16*t + c)*64 + 32*u + 8*q);
            }

        // ---- fused per-m residual update: S = W1@H^T ; H^T += W2@relu(S)^T
#pragma unroll
        for (int m = 0; m < 4; m++){
            bf16x8 B0 = bc(Hp[m][0]), B1 = bc(Hp[m][1]);
            f32x4 S[4];
#pragma unroll
            for (int t = 0; t < 4; t++){
                f32x4 s = {0.f, 0.f, 0.f, 0.f};
                s = __builtin_amdgcn_mfma_f32_16x16x32_bf16(W1f[t][0], B0, s, 0, 0, 0);
                s = __builtin_amdgcn_mfma_f32_16x16x32_bf16(W1f[t][1], B1, s, 0, 0, 0);
                S[t] = s;
            }
            u32x4 T0p, T1p;
            T0p.x = pk_bf16(fmaxf(S[0][0],0.f), fmaxf(S[0][1],0.f));
            T0p.y = pk_bf16(fmaxf(S[0][2],0.f), fmaxf(S[0][3],0.f));
            T0p.z = pk_bf16(fmaxf(S[1][0],0.f), fmaxf(S[1][1],0.f));
            T0p.w = pk_bf16(fmaxf(S[1][2],0.f), fmaxf(S[1][3],0.f));
            T1p.x = pk_bf16(fmaxf(S[2][0],0.f), fmaxf(S[2][1],0.f));
            T1p.y = pk_bf16(fmaxf(S[2][2],0.f), fmaxf(S[2][3],0.f));
            T1p.z = pk_bf16(fmaxf(S[3][0],0.f), fmaxf(S[3][1],0.f));
            T1p.w = pk_bf16(fmaxf(S[3][2],0.f), fmaxf(S[3][3],0.f));
            bf16x8 T0 = bc(T0p), T1 = bc(T1p);

            f32x4 h[4];
#pragma unroll
            for (int t = 0; t < 4; t++){
                unsigned wa = Hp[m][t >> 1][(t & 1)*2 + 0];
                unsigned wb = Hp[m][t >> 1][(t & 1)*2 + 1];
                f32x4 cc;
                cc[0] = bf_lo(wa); cc[1] = bf_hi(wa);
                cc[2] = bf_lo(wb); cc[3] = bf_hi(wb);
                cc = __builtin_amdgcn_mfma_f32_16x16x32_bf16(W2f[t][0], T0, cc, 0, 0, 0);
                cc = __builtin_amdgcn_mfma_f32_16x16x32_bf16(W2f[t][1], T1, cc, 0, 0, 0);
                h[t] = cc;
            }
            Hp[m][0].x = pk_bf16(h[0][0], h[0][1]);
            Hp[m][0].y = pk_bf16(h[0][2], h[0][3]);
            Hp[m][0].z = pk_bf16(h[1][0], h[1][1]);
            Hp[m][0].w = pk_bf16(h[1][2], h[1][3]);
            Hp[m][1].x = pk_bf16(h[2][0], h[2][1]);
            Hp[m][1].y = pk_bf16(h[2][2], h[2][3]);
            Hp[m][1].z = pk_bf16(h[3][0], h[3][1]);
            Hp[m][1].w = pk_bf16(h[3][2], h[3][3]);
        }
    }

    // ---- epilogue: u_a[point] = sum_f W1a[a][f] * H^T[f][point] ----
    float4 fa0[4], fa1[4], fa2[4];
#pragma unroll
    for (int t = 0; t < 4; t++){
        fa0[t] = *(const float4*)(W1a +       16*t + 4*q);
        fa1[t] = *(const float4*)(W1a +  64 + 16*t + 4*q);
        fa2[t] = *(const float4*)(W1a + 128 + 16*t + 4*q);
    }
    float u0 = 0.f, u1 = 0.f, u2 = 0.f;
#pragma unroll
    for (int m = 0; m < 4; m++){
        float p0 = 0.f, p1 = 0.f, p2 = 0.f;
#pragma unroll
        for (int t = 0; t < 4; t++){
            unsigned wa = Hp[m][t >> 1][(t & 1)*2 + 0];
            unsigned wb = Hp[m][t >> 1][(t & 1)*2 + 1];
            float h0 = bf_lo(wa), h1 = bf_hi(wa), h2 = bf_lo(wb), h3 = bf_hi(wb);
            p0 = fmaf(h0, fa0[t].x, p0); p0 = fmaf(h1, fa0[t].y, p0);
            p0 = fmaf(h2, fa0[t].z, p0); p0 = fmaf(h3, fa0[t].w, p0);
            p1 = fmaf(h0, fa1[t].x, p1); p1 = fmaf(h1, fa1[t].y, p1);
            p1 = fmaf(h2, fa1[t].z, p1); p1 = fmaf(h3, fa1[t].w, p1);
            p2 = fmaf(h0, fa2[t].x, p2); p2 = fmaf(h1, fa2[t].y, p2);
            p2 = fmaf(h2, fa2[t].z, p2); p2 = fmaf(h3, fa2[t].w, p2);
        }
        p0 += __shfl_xor(p0, 16, 64); p0 += __shfl_xor(p0, 32, 64);
        p1 += __shfl_xor(p1, 16, 64); p1 += __shfl_xor(p1, 32, 64);
        p2 += __shfl_xor(p2, 16, 64); p2 += __shfl_xor(p2, 32, 64);
        if (q == m){ u0 = p0; u1 = p1; u2 = p2; }
    }

    {
        int n = P0 + 16*q + c;
        if (n < N){
            float pxs = pos[n*3+0], pys = pos[n*3+1], pzs = pos[n*3+2];
            float t0 = tanhf(u0), t1 = tanhf(u1), t2 = tanhf(u2);
            float r0 = t0*W1b[0] + t1*W1b[1] + t2*W1b[2];
            float r1 = t0*W1b[3] + t1*W1b[4] + t2*W1b[5];
            float r2 = t0*W1b[6] + t1*W1b[7] + t2*W1b[8];
            float pdx = pxs + r0, pdy = pys + r1, pdz = pzs + r2;
            const float* Rb = Rm + b*9;
            float q0 = pdx*Rb[0] + pdy*Rb[3] + pdz*Rb[6];
            float q1 = pdx*Rb[1] + pdy*Rb[4] + pdz*Rb[7];
            size_t base = (size_t)b*N + n;
            out_res[base*3+0] = r0;  out_res[base*3+1] = r1;  out_res[base*3+2] = r2;
            out_pos_d[base*3+0] = pdx; out_pos_d[base*3+1] = pdy; out_pos_d[base*3+2] = pdz;
            out_proj_pos[base*2+0] = q0; out_proj_pos[base*2+1] = q1;

            // ---- fused bilinear splat ----
            float e0 = expf(ampvar[n]);
            float e1 = expf(ampvar[N+n]);
            float inv = amp[0] / (e0 + e1);
            float v0 = e0*inv, v1 = e1*inv;
            float pyf = (q0 + 0.5f) * 255.0f;
            float pxf = (q1 + 0.5f) * 255.0f;
            float fy0 = floorf(pyf), fx0 = floorf(pxf);
            int iy = (int)fy0, ix = (int)fx0;
            float fy = pyf - fy0, fx = pxf - fx0;
            float wy[2] = {1.f - fy, fy};
            float wx[2] = {1.f - fx, fx};
#pragma unroll
            for (int dy = 0; dy < 2; dy++)
#pragma unroll
                for (int dx = 0; dx < 2; dx++){
                    float w = wy[dy]*wx[dx];
                    int yi = min(max(iy+dy, 0), 255);
                    int xi = min(max(ix+dx, 0), 255);
                    int ty = yi - TO, tx = xi - TO;
                    if ((unsigned)ty < TS && (unsigned)tx < TS){
                        atomicAdd(&tile[ty*TS + tx],         v0*w);
                        atomicAdd(&tile[TS*TS + ty*TS + tx], v1*w);
                    } else {
                        atomicAdd(&proj_im[((size_t)(b*2+0)*256 + yi)*256 + xi], v0*w);
                        atomicAdd(&proj_im[((size_t)(b*2+1)*256 + yi)*256 + xi], v1*w);
                    }
                }
        }
    }

    __syncthreads();
    for (int i = threadIdx.x; i < TS*TS; i += 256){
        int ty = i >> 4, tx = i & (TS-1);
        float v = tile[i];
        if (v != 0.f) atomicAdd(&proj_im[((size_t)(b*2+0)*256 + TO+ty)*256 + TO+tx], v);
        v = tile[TS*TS + i];
        if (v != 0.f) atomicAdd(&proj_im[((size_t)(b*2+1)*256 + TO+ty)*256 + TO+tx], v);
    }
}

// ---------------- DFT pass 1: rows, sparse-aware + LDS twiddle table -------
__launch_bounds__(256)
__global__ void dft_rows_kernel(const float* __restrict__ proj_im, float2* __restrict__ S)
{
    int b = blockIdx.y, y = blockIdx.x;
    __shared__ float2 row[256];
    __shared__ float2 tw[256];
    __shared__ unsigned long long nzm[4];
    int k = threadIdx.x;
    {
        float s, c;
        sincosf(-6.283185307179586f * (float)k / 256.0f, &s, &c);
        tw[k] = make_float2(c, s);
    }
    const float* im0 = proj_im + ((size_t)(b*2+0)*256 + y)*256;
    const float* im1 = proj_im + ((size_t)(b*2+1)*256 + y)*256;
    float2 my = make_float2(im0[k], im1[k]);
    row[k] = my;
    unsigned long long bal = __ballot(my.x != 0.f || my.y != 0.f);
    if ((k & 63) == 0) nzm[k >> 6] = bal;
    __syncthreads();

    float2 acc = make_float2(0.f, 0.f);
#pragma unroll 1
    for (int g = 0; g < 4; g++){
        unsigned long long mm = nzm[g];
        while (mm){
            int x = (g << 6) + __ffsll((long long)mm) - 1;
            mm &= mm - 1;
            float2 zv = row[x];
            float2 t = tw[(k * x) & 255];
            acc.x = fmaf(zv.x, t.x, fmaf(-zv.y, t.y, acc.x));
            acc.y = fmaf(zv.x, t.y, fmaf( zv.y, t.x, acc.y));
        }
    }
    S[((size_t)b*256 + y)*256 + k] = acc;
}

// ---------------- DFT pass 2: column-tile slab, sparse rows, IN PLACE ------
__launch_bounds__(256)
__global__ void dft_cols_kernel(float2* __restrict__ S)
{
    __shared__ float2 slab[256][KXT + 1];
    __shared__ float2 tw[256];
    __shared__ unsigned long long wmask[4];
    __shared__ int rows[256];
    __shared__ int nrows_s;
    int b = blockIdx.y, kx0 = blockIdx.x * KXT;
    int tid = threadIdx.x;
    float2* Sb = S + (size_t)b*65536;

    {
        float s, c;
        sincosf(-6.283185307179586f * (float)tid / 256.0f, &s, &c);
        tw[tid] = make_float2(c, s);
    }
#pragma unroll 1
    for (int r0 = 0; r0 < 256; r0 += 16){
        int y = r0 + (tid >> 4), j = tid & 15;
        slab[y][j] = Sb[(size_t)y*256 + kx0 + j];
    }
    __syncthreads();

    bool nz = false;
#pragma unroll
    for (int j = 0; j < KXT; j++){
        float2 v = slab[tid][j];
        nz = nz || (v.x != 0.f) || (v.y != 0.f);
    }
    unsigned long long m = __ballot(nz);
    int wv = tid >> 6, lane = tid & 63;
    if (lane == 0) wmask[wv] = m;
    __syncthreads();
    if (nz){
        int off = 0;
        for (int w2 = 0; w2 < 4; w2++) if (w2 < wv) off += __popcll(wmask[w2]);
        unsigned long long below = (lane == 0) ? 0ULL : (m & ((1ULL << lane) - 1ULL));
        off += __popcll(below);
        rows[off] = tid;
    }
    if (tid == 0){
        int n = 0;
        for (int w2 = 0; w2 < 4; w2++) n += __popcll(wmask[w2]);
        nrows_s = n;
    }
    __syncthreads();
    int nr = nrows_s;

    int ky = tid;
    float2 acc[KXT];
#pragma unroll
    for (int j = 0; j < KXT; j++) acc[j] = make_float2(0.f, 0.f);
#pragma unroll 1
    for (int r = 0; r < nr; r++){
        int y = rows[r];
        float2 t = tw[(ky * y) & 255];
#pragma unroll
        for (int j = 0; j < KXT; j++){
            float2 zv = slab[y][j];
            acc[j].x = fmaf(zv.x, t.x, fmaf(-zv.y, t.y, acc[j].x));
            acc[j].y = fmaf(zv.x, t.y, fmaf( zv.y, t.x, acc[j].y));
        }
    }
#pragma unroll
    for (int j = 0; j < KXT; j++)
        Sb[(size_t)ky*256 + kx0 + j] = acc[j];   // Z[b][ky][kx]
}

// ---------------- Hermitian unpack + CTF filter + channel sum --------------
__launch_bounds__(256)
__global__ void combine_kernel(const float2* __restrict__ Z,
                               const float* __restrict__ A, const float* __restrict__ Bc,
                               float* __restrict__ outP, int pairs)
{
    int gid = blockIdx.x*256 + threadIdx.x;
    int b = gid >> 16;
    int lin = gid & 65535;
    int ky = lin >> 8, kx = lin & 255;
    int mky = (256 - ky) & 255, mkx = (256 - kx) & 255;
    int mlin = mky*256 + mkx;
    if (lin > mlin) return;   // pair owner only
    const float2* Zb = Z + (size_t)b*65536;
    float2 Zk = Zb[lin];
    float2 Zm = Zb[mlin];
    float Er = 0.5f*(Zk.x + Zm.x), Ei = 0.5f*(Zk.y - Zm.y);
    float Or = 0.5f*(Zk.y + Zm.y), Oi = 0.5f*(Zm.x - Zk.x);
    float fy = (ky < 128) ? (float)ky : (float)(ky - 256);
    float fx = (kx < 128) ? (float)kx : (float)(kx - 256);
    float rad = rintf(sqrtf(fy*fy + fx*fx));
    float a0 = A[0], a1 = A[1], b0 = Bc[0], b1 = Bc[1];
    float F0 = a0*a0*expf(-b0*b0*rad);
    float F1 = a1*a1*expf(-b1*b1*rad);
    float2 P = make_float2(fmaf(F0, Er, F1*Or), fmaf(F0, Ei, F1*Oi));
    if (pairs){
        float2* O = (float2*)outP + (size_t)b*65536;
        O[lin] = P;
        if (mlin != lin) O[mlin] = make_float2(P.x, -P.y);
    } else {
        float* O = outP + (size_t)b*65536;
        O[lin] = P.x;
        if (mlin != lin) O[mlin] = P.x;
    }
}

extern "C" void kernel_launch(void* const* d_in, const int* in_sizes, int n_in,
                              void* d_out, int out_size, void* d_ws, size_t ws_size,
                              hipStream_t stream)
{
    const float* z      = (const float*)d_in[0];
    const float* r      = (const float*)d_in[1];
    const float* pos    = (const float*)d_in[2];
    const float* amp    = (const float*)d_in[3];
    const float* ampvar = (const float*)d_in[4];
    const float* W0     = (const float*)d_in[5];
    const float* Wres1  = (const float*)d_in[6];
    const float* Wres2  = (const float*)d_in[7];
    const float* W1a    = (const float*)d_in[8];
    const float* W1b    = (const float*)d_in[9];
    const float* A      = (const float*)d_in[10];
    const float* Bc     = (const float*)d_in[11];

    int B = in_sizes[0] / 16;     // 16
    int N = in_sizes[2] / 3;      // 20000

    size_t nIm = (size_t)B * 65536;
    long long tailSz   = (long long)(2*nIm) + 8LL*B*N;
    long long projSize = (long long)out_size - tailSz;
    int pairs = (projSize >= (long long)(2*nIm)) ? 1 : 0;

    float* out = (float*)d_out;
    float* out_proj    = out;
    float* out_projim  = out + projSize;
    float* out_projpos = out_projim + 2*nIm;          // B*N*2
    float* out_posd    = out_projpos + (size_t)B*N*2; // B*N*3
    float* out_res     = out_posd    + (size_t)B*N*3; // B*N*3

    float* scratch = out_proj;   // dead until dft_rows; decoder consumes first

    float2* S;
    if (pairs)                                         S = (float2*)out_proj;
    else if (ws_size >= (size_t)(2*nIm)*sizeof(float)) S = (float2*)d_ws;
    else                                               S = (float2*)out_proj;

    int n4 = (int)(2*nIm/4);
    int zblocks = (n4 + 255)/256;
    setup_kernel<<<17 + zblocks, 256, 0, stream>>>(r, z, W0, Wres1, Wres2,
                                                   scratch, (float4*)out_projim,
                                                   n4, B);

    dim3 dgrid((N + 255)/256, B);
    decoder_kernel<<<dgrid, 256, 0, stream>>>(pos, W0, scratch, W1a, W1b,
                                              ampvar, amp,
                                              out_projpos, out_posd, out_res,
                                              out_projim, N);

    dim3 fgrid(256, B);
    dft_rows_kernel<<<fgrid, 256, 0, stream>>>(out_projim, S);
    dim3 cgrid(256/KXT, B);
    dft_cols_kernel<<<cgrid, 256, 0, stream>>>(S);
    combine_kernel<<<(int)(nIm/256), 256, 0, stream>>>(S, A, Bc, out_proj, pairs);
}